// Round 2
// baseline (6649.426 us; speedup 1.0000x reference)
//
#include <hip/hip_runtime.h>
#include <hip/hip_fp16.h>

// Fused STAMP session-attention kernel, MI355X (gfx950).
// One block per batch (B=2048), 512 threads = 8 waves.
// Phases per batch:
//   P0: alias row -> LDS
//   P1: K^T, V (relu-projected, f16) -> LDS for s in [0,len)
//   pre-pass: dec[len-1] -> last_p (f32 LDS) ; out[:,128:256] = last_p
//   main: per wave w, rows t = t0+w: stage x, Q=relu(x@Wq), scores=QK^T/sqrt(D),
//         wave-parallel softmax, dec = attn@V + x, seq_p = dec@u_w2,
//         coef = sum(sigmoid(last_p+seq_p+u_b)*u_v), out1 += coef*dec.
// Rows t>=len are provably dead (query mask) and skipped entirely.

#define T_N 200
#define D_N 128
#define KT_ST 208   // kt row stride in halfs (>= 204 for b64 straddle reads)

struct Smem {
  float  xbuf[16][D_N];    //  8192 B  staging (P1: 16 rows; main: row per wave)
  float  qbuf[8][D_N];     //  4096 B  Q per wave (also last_p partials)
  float  decbuf[8][D_N];   //  4096 B  dec per wave
  float  pbuf[8][256];     //  8192 B  softmax probs per wave (also out1 partials)
  float  lastp[D_N];       //   512 B
  __half kt[D_N][KT_ST];   // 53248 B  K transposed: kt[k][s]
  __half v[T_N][D_N];      // 51200 B  V row-major
  int    alias[T_N];       //   800 B
};                         // total 130,336 B -> 1 block/CU

__device__ __forceinline__ float wave_max(float x) {
  #pragma unroll
  for (int off = 32; off > 0; off >>= 1) x = fmaxf(x, __shfl_xor(x, off, 64));
  return x;
}
__device__ __forceinline__ float wave_sum(float x) {
  #pragma unroll
  for (int off = 32; off > 0; off >>= 1) x += __shfl_xor(x, off, 64);
  return x;
}

__global__ __launch_bounds__(512, 2)
void stamp_fused(const float* __restrict__ re, const int* __restrict__ aliasg,
                 const int* __restrict__ slen,
                 const float* __restrict__ Wq, const float* __restrict__ Wk,
                 const float* __restrict__ Wv, const float* __restrict__ uw1,
                 const float* __restrict__ uw2, const float* __restrict__ ub,
                 const float* __restrict__ uv, float* __restrict__ out)
{
  extern __shared__ char smraw[];
  Smem& sm = *reinterpret_cast<Smem*>(smraw);
  const int tid  = threadIdx.x;
  const int lane = tid & 63;
  const int w    = tid >> 6;
  const int b    = blockIdx.x;
  const int len  = slen[b];
  const float* __restrict__ reb = re + (size_t)b * (T_N * D_N);

  if (tid < T_N) sm.alias[tid] = aliasg[b * T_N + tid];
  __syncthreads();

  // ---------------- P1: K^T and V (f16) for rows [0, len) ----------------
  {
    const int j  = tid >> 5;     // 0..15 (row within chunk)
    const int u  = tid & 31;
    const int e0 = u << 2;       // output col quad
    for (int s0 = 0; s0 < len; s0 += 16) {
      const int nr = min(16, len - s0);
      if (j < nr) {
        const float* xr = reb + (size_t)sm.alias[s0 + j] * D_N;
        *reinterpret_cast<float4*>(&sm.xbuf[j][e0]) =
            *reinterpret_cast<const float4*>(xr + e0);
      }
      __syncthreads();
      if (j < nr) {
        float aK[4] = {0.f,0.f,0.f,0.f}, aV[4] = {0.f,0.f,0.f,0.f};
        for (int d0 = 0; d0 < D_N; d0 += 4) {
          float4 x4 = *reinterpret_cast<const float4*>(&sm.xbuf[j][d0]);
          float xs[4] = {x4.x, x4.y, x4.z, x4.w};
          #pragma unroll
          for (int dd = 0; dd < 4; ++dd) {
            const int d = d0 + dd;
            float4 k4 = *reinterpret_cast<const float4*>(Wk + d * D_N + e0);
            float4 v4 = *reinterpret_cast<const float4*>(Wv + d * D_N + e0);
            aK[0] += xs[dd]*k4.x; aK[1] += xs[dd]*k4.y;
            aK[2] += xs[dd]*k4.z; aK[3] += xs[dd]*k4.w;
            aV[0] += xs[dd]*v4.x; aV[1] += xs[dd]*v4.y;
            aV[2] += xs[dd]*v4.z; aV[3] += xs[dd]*v4.w;
          }
        }
        const int s = s0 + j;
        #pragma unroll
        for (int i = 0; i < 4; ++i)
          sm.kt[e0 + i][s] = __float2half(fmaxf(aK[i], 0.f));
        union { __half2 h; unsigned u32; } c01, c23;
        c01.h = __floats2half2_rn(fmaxf(aV[0],0.f), fmaxf(aV[1],0.f));
        c23.h = __floats2half2_rn(fmaxf(aV[2],0.f), fmaxf(aV[3],0.f));
        *reinterpret_cast<uint2*>(&sm.v[s][e0]) = make_uint2(c01.u32, c23.u32);
      }
      __syncthreads();
    }
    // zero kt tail cols [len, len+4): scores b64 straddle reads touch <= len+2
    {
      const int k = tid >> 2;
      const int s = len + (tid & 3);   // <= 203 < 208, always in-bounds
      sm.kt[k][s] = __float2half(0.f);
    }
    __syncthreads();
  }

  const int tlast = len - 1;
  const float2 ub2 = *reinterpret_cast<const float2*>(ub + 2*lane);
  const float2 uv2 = *reinterpret_cast<const float2*>(uv + 2*lane);
  float2 out1 = make_float2(0.f, 0.f);

  // pass 0: only the 8-row block containing tlast (produces decbuf[tlast&7] -> last_p)
  // pass 1: all blocks, with STAMP accumulation
  for (int pass = 0; pass < 2; ++pass) {
    const int t0b = pass ? 0   : (tlast & ~7);
    const int t0e = pass ? len : (tlast & ~7) + 1;
    for (int t0 = t0b; t0 < t0e; t0 += 8) {
      __syncthreads();               // bound wave drift (L1 weight-stream locality)
      const int t = t0 + w;
      if (t < len) {
        // (a) stage x row (per wave)
        const float* xr = reb + (size_t)sm.alias[t] * D_N;
        *reinterpret_cast<float2*>(&sm.xbuf[w][2*lane]) =
            *reinterpret_cast<const float2*>(xr + 2*lane);
        // (b) Q = relu(x @ Wq), per wave (lane -> e pair)
        float2 q = make_float2(0.f, 0.f);
        for (int d0 = 0; d0 < D_N; d0 += 4) {
          float4 x4 = *reinterpret_cast<const float4*>(&sm.xbuf[w][d0]);
          float xs[4] = {x4.x, x4.y, x4.z, x4.w};
          #pragma unroll
          for (int dd = 0; dd < 4; ++dd) {
            float2 w2 = *reinterpret_cast<const float2*>(Wq + (d0+dd)*D_N + 2*lane);
            q.x += xs[dd]*w2.x; q.y += xs[dd]*w2.y;
          }
        }
        q.x = fmaxf(q.x, 0.f); q.y = fmaxf(q.y, 0.f);
        *reinterpret_cast<float2*>(&sm.qbuf[w][2*lane]) = q;
        // (c) scores (lane -> s quad) + wave-parallel softmax
        float sc[4] = {0.f,0.f,0.f,0.f};
        const int s0l = lane << 2;
        const bool rd = (s0l < len);
        for (int k0 = 0; k0 < D_N; k0 += 4) {
          float4 q4 = *reinterpret_cast<const float4*>(&sm.qbuf[w][k0]);
          float qs[4] = {q4.x, q4.y, q4.z, q4.w};
          #pragma unroll
          for (int kk = 0; kk < 4; ++kk) {
            if (rd) {
              uint2 kr = *reinterpret_cast<const uint2*>(&sm.kt[k0+kk][s0l]);
              union { unsigned u32; __half2 h; } a, bb;
              a.u32 = kr.x; bb.u32 = kr.y;
              float2 f01 = __half22float2(a.h);
              float2 f23 = __half22float2(bb.h);
              sc[0] += qs[kk]*f01.x; sc[1] += qs[kk]*f01.y;
              sc[2] += qs[kk]*f23.x; sc[3] += qs[kk]*f23.y;
            }
          }
        }
        const float scale = 0.08838834764831845f;  // 1/sqrt(128)
        float mloc = -3.0e38f;
        #pragma unroll
        for (int i = 0; i < 4; ++i) {
          sc[i] = (s0l + i < len) ? sc[i]*scale : -3.0e38f;
          mloc = fmaxf(mloc, sc[i]);
        }
        const float M = wave_max(mloc);
        float p[4]; float ps = 0.f;
        #pragma unroll
        for (int i = 0; i < 4; ++i) {
          p[i] = (s0l + i < len) ? __expf(sc[i] - M) : 0.f;
          ps += p[i];
        }
        const float S  = wave_sum(ps);
        const float rS = 1.0f / S;
        *reinterpret_cast<float4*>(&sm.pbuf[w][s0l]) =
            make_float4(p[0]*rS, p[1]*rS, p[2]*rS, p[3]*rS);
        // (d) dec = attn @ V + x   (lane -> e quad, split s over wave halves)
        const int eh = lane & 31, sh = lane >> 5;
        const int e0 = eh << 2;
        float acc[4] = {0.f,0.f,0.f,0.f};
        for (int s = sh; s < len; s += 2) {
          const float pp = sm.pbuf[w][s];
          uint2 vr = *reinterpret_cast<const uint2*>(&sm.v[s][e0]);
          union { unsigned u32; __half2 h; } a, bb;
          a.u32 = vr.x; bb.u32 = vr.y;
          float2 f01 = __half22float2(a.h);
          float2 f23 = __half22float2(bb.h);
          acc[0] += pp*f01.x; acc[1] += pp*f01.y;
          acc[2] += pp*f23.x; acc[3] += pp*f23.y;
        }
        #pragma unroll
        for (int i = 0; i < 4; ++i) acc[i] += __shfl_xor(acc[i], 32, 64);
        if (sh == 0) {
          float4 xres = *reinterpret_cast<const float4*>(&sm.xbuf[w][e0]);
          *reinterpret_cast<float4*>(&sm.decbuf[w][e0]) =
              make_float4(acc[0]+xres.x, acc[1]+xres.y, acc[2]+xres.z, acc[3]+xres.w);
        }
        // (e) STAMP: seq_p, sigmoid, coef, accumulate out1 (per wave, own row)
        if (pass) {
          float2 sp = make_float2(0.f, 0.f);
          for (int d0 = 0; d0 < D_N; d0 += 4) {
            float4 dc4 = *reinterpret_cast<const float4*>(&sm.decbuf[w][d0]);
            float dsv[4] = {dc4.x, dc4.y, dc4.z, dc4.w};
            #pragma unroll
            for (int dd = 0; dd < 4; ++dd) {
              float2 w2 = *reinterpret_cast<const float2*>(uw2 + (d0+dd)*D_N + 2*lane);
              sp.x += dsv[dd]*w2.x; sp.y += dsv[dd]*w2.y;
            }
          }
          float2 lp2 = *reinterpret_cast<const float2*>(&sm.lastp[2*lane]);
          float mx = 1.f/(1.f + __expf(-(lp2.x + sp.x + ub2.x)));
          float my = 1.f/(1.f + __expf(-(lp2.y + sp.y + ub2.y)));
          float cf = mx*uv2.x + my*uv2.y;
          cf = wave_sum(cf);
          float2 dp = *reinterpret_cast<const float2*>(&sm.decbuf[w][2*lane]);
          out1.x += cf*dp.x; out1.y += cf*dp.y;
        }
      }
    }
    if (!pass) {
      __syncthreads();
      // last_p = dec[len-1] @ u_w1 ; also emit out[:,128:256]
      const int e = tid & 127, g = tid >> 7;
      const int wl = tlast & 7;
      float acc = 0.f;
      for (int i = 0; i < 32; ++i) {
        const int d = (g << 5) + i;
        acc += sm.decbuf[wl][d] * uw1[d * D_N + e];
      }
      sm.qbuf[g][e] = acc;              // reuse qbuf as partials
      __syncthreads();
      if (tid < D_N) {
        const float lp = sm.qbuf[0][tid] + sm.qbuf[1][tid]
                       + sm.qbuf[2][tid] + sm.qbuf[3][tid];
        sm.lastp[tid] = lp;
        out[(size_t)b * 256 + 128 + tid] = lp;
      }
      __syncthreads();
    }
  }

  // final: out1 = sum over waves
  __syncthreads();
  sm.pbuf[w][2*lane]     = out1.x;
  sm.pbuf[w][2*lane + 1] = out1.y;
  __syncthreads();
  if (tid < 64) {
    float sx = 0.f, sy = 0.f;
    #pragma unroll
    for (int ww = 0; ww < 8; ++ww) {
      float2 v2 = *reinterpret_cast<const float2*>(&sm.pbuf[ww][2*tid]);
      sx += v2.x; sy += v2.y;
    }
    *reinterpret_cast<float2*>(out + (size_t)b * 256 + 2*tid) = make_float2(sx, sy);
  }
}

extern "C" void kernel_launch(void* const* d_in, const int* in_sizes, int n_in,
                              void* d_out, int out_size, void* d_ws, size_t ws_size,
                              hipStream_t stream) {
  (void)n_in; (void)d_ws; (void)ws_size; (void)out_size;
  const float* re    = (const float*)d_in[0];
  const int*   alias = (const int*)  d_in[1];
  const int*   slen  = (const int*)  d_in[2];
  const float* Wq    = (const float*)d_in[3];
  const float* Wk    = (const float*)d_in[4];
  const float* Wv    = (const float*)d_in[5];
  const float* uw1   = (const float*)d_in[6];
  const float* uw2   = (const float*)d_in[7];
  const float* ub    = (const float*)d_in[8];
  const float* uv    = (const float*)d_in[9];
  float* out = (float*)d_out;
  const int B = in_sizes[2];           // seq_len has B elements

  // >64KB dynamic LDS opt-in (idempotent, capture-safe host call)
  hipFuncSetAttribute(reinterpret_cast<const void*>(stamp_fused),
                      hipFuncAttributeMaxDynamicSharedMemorySize,
                      (int)sizeof(Smem));
  stamp_fused<<<B, 512, sizeof(Smem), stream>>>(re, alias, slen, Wq, Wk, Wv,
                                                uw1, uw2, ub, uv, out);
}

// Round 3
// 3558.972 us; speedup vs baseline: 1.8684x; 1.8684x over previous
//
#include <hip/hip_runtime.h>
#include <hip/hip_fp16.h>

// Fused STAMP session-attention, MI355X (gfx950). One block per batch, 8 waves.
// R3 change vs R2: weights (Wq,Wk,Wv,u_w2) are REGISTER-RESIDENT per wave
// (wave w owns output cols 16w..16w+15; lane (g,cl) holds rows 32g..32g+31 of
// col 16w+cl). All projections are block-cooperative: x/dec broadcast from LDS
// (+4-float skew per 32-block to avoid 4-way g-conflicts), 2x shfl_xor reduce.
// This removes ~25.6 MB/block of L2 weight streaming (the round-2 latency
// source: VALUBusy 13.7%, 2 waves/SIMD). Attention core (scores/softmax/PV)
// unchanged from the verified round-2 kernel.

#define T_N 200
#define D_N 128
#define KT_ST 208                 // kt row stride (halfs); b64 straddle-safe
#define XST 140                   // skewed row stride (floats) for xbuf/decbuf
#define XIDX(d) ((d) + 4*((d) >> 5))   // +4 floats per 32-block: g-groups hit
                                       // distinct banks on broadcast reads

struct Smem {
  float  xbuf[16][XST];    //  8960 B  staging (P1: 16 rows; main: row per wave)
  float  qbuf[8][D_N];     //  4096 B  Q rows (also last_p partials)
  float  decbuf[8][XST];   //  4480 B  dec rows (skewed)
  float  pbuf[8][256];     //  8192 B  softmax probs per wave (also out1 red.)
  float  lastp[D_N];       //   512 B
  float  coefw[8][8];      //   256 B  per-row per-wave coef partials
  __half kt[D_N][KT_ST];   // 53248 B  K transposed: kt[k][s]
  __half v[T_N][D_N];      // 51200 B  V row-major
  int    alias[T_N];       //   800 B
};                         // total 131,744 B -> 1 block/CU, 8 waves

__device__ __forceinline__ float wave_max(float x) {
  #pragma unroll
  for (int off = 32; off > 0; off >>= 1) x = fmaxf(x, __shfl_xor(x, off, 64));
  return x;
}
__device__ __forceinline__ float wave_sum(float x) {
  #pragma unroll
  for (int off = 32; off > 0; off >>= 1) x += __shfl_xor(x, off, 64);
  return x;
}
// reduce the 4 g-groups (lanes cl, cl+16, cl+32, cl+48) -> all lanes get sum
__device__ __forceinline__ float gsum(float x) {
  x += __shfl_xor(x, 16, 64);
  x += __shfl_xor(x, 32, 64);
  return x;
}
// sum over the 16 cl lanes of each g-group (all groups hold identical values)
__device__ __forceinline__ float colsum16(float x) {
  x += __shfl_xor(x, 1, 64); x += __shfl_xor(x, 2, 64);
  x += __shfl_xor(x, 4, 64); x += __shfl_xor(x, 8, 64);
  return x;
}

__global__ __launch_bounds__(512, 2)
void stamp_fused(const float* __restrict__ re, const int* __restrict__ aliasg,
                 const int* __restrict__ slen,
                 const float* __restrict__ Wq, const float* __restrict__ Wk,
                 const float* __restrict__ Wv, const float* __restrict__ uw1,
                 const float* __restrict__ uw2, const float* __restrict__ ub,
                 const float* __restrict__ uv, float* __restrict__ out)
{
  extern __shared__ char smraw[];
  Smem& sm = *reinterpret_cast<Smem*>(smraw);
  const int tid  = threadIdx.x;
  const int lane = tid & 63;
  const int w    = tid >> 6;
  const int cl   = lane & 15;
  const int g    = lane >> 4;
  const int cw   = (w << 4) | cl;   // this lane's output column
  const int d0g  = g << 5;          // this lane's input-row block
  const int b    = blockIdx.x;
  const int len  = slen[b];
  const float* __restrict__ reb = re + (size_t)b * (T_N * D_N);

  if (tid < T_N) sm.alias[tid] = aliasg[b * T_N + tid];

  // ---- register-resident weights: W[d0g+i][cw], i = 0..31 (one-time) ----
  float wq[32], wk[32], wv[32], w2[32];
  #pragma unroll
  for (int i = 0; i < 32; ++i) {
    const int off = (d0g + i) * D_N + cw;
    wq[i] = Wq[off]; wk[i] = Wk[off]; wv[i] = Wv[off]; w2[i] = uw2[off];
  }
  const float ub_c = ub[cw];
  const float uv_c = uv[cw];
  __syncthreads();

  // ---------------- P1: K^T and V (f16) for rows [0, len) ----------------
  {
    const int j  = tid >> 5;     // staging row 0..15
    const int e0 = (tid & 31) << 2;
    for (int s0 = 0; s0 < len; s0 += 16) {
      const int nr = min(16, len - s0);
      __syncthreads();                       // xbuf reuse guard
      if (j < nr) {
        const float* xr = reb + (size_t)sm.alias[s0 + j] * D_N;
        *reinterpret_cast<float4*>(&sm.xbuf[j][XIDX(e0)]) =
            *reinterpret_cast<const float4*>(xr + e0);
      }
      __syncthreads();
      for (int r = 0; r < nr; ++r) {
        float ak0=0,ak1=0,ak2=0,ak3=0, av0=0,av1=0,av2=0,av3=0;
        #pragma unroll
        for (int i0 = 0; i0 < 32; i0 += 4) {
          float4 x4 = *reinterpret_cast<const float4*>(&sm.xbuf[r][XIDX(d0g + i0)]);
          ak0 += x4.x*wk[i0];   ak1 += x4.y*wk[i0+1];
          ak2 += x4.z*wk[i0+2]; ak3 += x4.w*wk[i0+3];
          av0 += x4.x*wv[i0];   av1 += x4.y*wv[i0+1];
          av2 += x4.z*wv[i0+2]; av3 += x4.w*wv[i0+3];
        }
        const float kv = gsum((ak0+ak1)+(ak2+ak3));
        const float vv = gsum((av0+av1)+(av2+av3));
        if (g == 0) {
          const int s = s0 + r;
          sm.kt[cw][s] = __float2half(fmaxf(kv, 0.f));
          sm.v[s][cw]  = __float2half(fmaxf(vv, 0.f));
        }
      }
    }
    __syncthreads();
    // zero kt tail cols [len, len+4): scores b64 straddle reads touch <= len+2
    sm.kt[tid >> 2][len + (tid & 3)] = __float2half(0.f);
    __syncthreads();
  }

  const int tlast = len - 1;
  float2 out1 = make_float2(0.f, 0.f);

  // pass 0: only the group containing tlast (-> decbuf -> last_p)
  // pass 1: all groups, with STAMP accumulation
  for (int pass = 0; pass < 2; ++pass) {
    const int t0b = pass ? 0   : (tlast & ~7);
    const int t0e = pass ? len : (tlast & ~7) + 1;
    for (int t0 = t0b; t0 < t0e; t0 += 8) {
      const int rmax = min(8, len - t0);
      __syncthreads();                 // xbuf/qbuf/decbuf/coefw reuse guard
      const int t = t0 + w;
      // (a) stage x rows (wave w -> its row)
      if (t < len) {
        const float* xr = reb + (size_t)sm.alias[t] * D_N;
        *reinterpret_cast<float2*>(&sm.xbuf[w][XIDX(2*lane)]) =
            *reinterpret_cast<const float2*>(xr + 2*lane);
      }
      __syncthreads();                 // x visible to all waves
      // (b) Q = relu(x @ Wq): cooperative, wave w -> cols cw, all rows
      for (int r = 0; r < rmax; ++r) {
        float a0=0,a1=0,a2=0,a3=0;
        #pragma unroll
        for (int i0 = 0; i0 < 32; i0 += 4) {
          float4 x4 = *reinterpret_cast<const float4*>(&sm.xbuf[r][XIDX(d0g + i0)]);
          a0 += x4.x*wq[i0];   a1 += x4.y*wq[i0+1];
          a2 += x4.z*wq[i0+2]; a3 += x4.w*wq[i0+3];
        }
        const float q = gsum((a0+a1)+(a2+a3));
        if (g == 0) sm.qbuf[r][cw] = fmaxf(q, 0.f);
      }
      __syncthreads();                 // Q visible
      // (c,d) scores + softmax + PV: per wave, own row (unchanged core)
      if (t < len) {
        float sc[4] = {0.f,0.f,0.f,0.f};
        const int s0l = lane << 2;
        const bool rd = (s0l < len);
        for (int k0 = 0; k0 < D_N; k0 += 4) {
          float4 q4 = *reinterpret_cast<const float4*>(&sm.qbuf[w][k0]);
          float qs[4] = {q4.x, q4.y, q4.z, q4.w};
          #pragma unroll
          for (int kk = 0; kk < 4; ++kk) {
            if (rd) {
              uint2 kr = *reinterpret_cast<const uint2*>(&sm.kt[k0+kk][s0l]);
              union { unsigned u32; __half2 h; } a, bb;
              a.u32 = kr.x; bb.u32 = kr.y;
              float2 f01 = __half22float2(a.h);
              float2 f23 = __half22float2(bb.h);
              sc[0] += qs[kk]*f01.x; sc[1] += qs[kk]*f01.y;
              sc[2] += qs[kk]*f23.x; sc[3] += qs[kk]*f23.y;
            }
          }
        }
        const float scale = 0.08838834764831845f;  // 1/sqrt(128)
        float mloc = -3.0e38f;
        #pragma unroll
        for (int i = 0; i < 4; ++i) {
          sc[i] = (s0l + i < len) ? sc[i]*scale : -3.0e38f;
          mloc = fmaxf(mloc, sc[i]);
        }
        const float M = wave_max(mloc);
        float p[4]; float ps = 0.f;
        #pragma unroll
        for (int i = 0; i < 4; ++i) {
          p[i] = (s0l + i < len) ? __expf(sc[i] - M) : 0.f;
          ps += p[i];
        }
        const float S  = wave_sum(ps);
        const float rS = 1.0f / S;
        *reinterpret_cast<float4*>(&sm.pbuf[w][s0l]) =
            make_float4(p[0]*rS, p[1]*rS, p[2]*rS, p[3]*rS);
        // dec = attn @ V + x  (lane -> e quad, s split over wave halves)
        const int eh = lane & 31, sh = lane >> 5;
        const int e0 = eh << 2;
        float acc[4] = {0.f,0.f,0.f,0.f};
        for (int s = sh; s < len; s += 2) {
          const float pp = sm.pbuf[w][s];
          uint2 vr = *reinterpret_cast<const uint2*>(&sm.v[s][e0]);
          union { unsigned u32; __half2 h; } a, bb;
          a.u32 = vr.x; bb.u32 = vr.y;
          float2 f01 = __half22float2(a.h);
          float2 f23 = __half22float2(bb.h);
          acc[0] += pp*f01.x; acc[1] += pp*f01.y;
          acc[2] += pp*f23.x; acc[3] += pp*f23.y;
        }
        #pragma unroll
        for (int i = 0; i < 4; ++i) acc[i] += __shfl_xor(acc[i], 32, 64);
        if (sh == 0) {
          float4 xres = *reinterpret_cast<const float4*>(&sm.xbuf[w][XIDX(e0)]);
          *reinterpret_cast<float4*>(&sm.decbuf[w][XIDX(e0)]) =
              make_float4(acc[0]+xres.x, acc[1]+xres.y, acc[2]+xres.z, acc[3]+xres.w);
        }
      }
      __syncthreads();                 // decbuf visible
      // (e) STAMP: cooperative seq_p/coef partials, then per-wave out1
      if (pass) {
        const float lp_c = sm.lastp[cw];
        for (int r = 0; r < rmax; ++r) {
          float a0=0,a1=0,a2=0,a3=0;
          #pragma unroll
          for (int i0 = 0; i0 < 32; i0 += 4) {
            float4 d4 = *reinterpret_cast<const float4*>(&sm.decbuf[r][XIDX(d0g + i0)]);
            a0 += d4.x*w2[i0];   a1 += d4.y*w2[i0+1];
            a2 += d4.z*w2[i0+2]; a3 += d4.w*w2[i0+3];
          }
          const float sp = gsum((a0+a1)+(a2+a3));
          const float m  = 1.f/(1.f + __expf(-(lp_c + sp + ub_c)));
          const float contrib = colsum16(m * uv_c);   // wave's 16-col partial
          if (lane == 0) sm.coefw[r][w] = contrib;
        }
        __syncthreads();               // coefw visible
        if (t < len) {
          float coef = 0.f;
          #pragma unroll
          for (int ww = 0; ww < 8; ++ww) coef += sm.coefw[w][ww];
          float2 dp = *reinterpret_cast<const float2*>(&sm.decbuf[w][XIDX(2*lane)]);
          out1.x += coef*dp.x; out1.y += coef*dp.y;
        }
      }
    }
    if (!pass) {
      __syncthreads();
      // last_p = dec[len-1] @ u_w1 ; also emit out[:,128:256]
      const int e = tid & 127, gg = tid >> 7;
      const int wl = tlast & 7;
      float acc = 0.f;
      for (int i = 0; i < 32; ++i) {
        const int d = (gg << 5) + i;
        acc += sm.decbuf[wl][XIDX(d)] * uw1[d * D_N + e];
      }
      sm.qbuf[gg][e] = acc;            // reuse qbuf as partials
      __syncthreads();
      if (tid < D_N) {
        const float lp = sm.qbuf[0][tid] + sm.qbuf[1][tid]
                       + sm.qbuf[2][tid] + sm.qbuf[3][tid];
        sm.lastp[tid] = lp;
        out[(size_t)b * 256 + 128 + tid] = lp;
      }
      __syncthreads();
    }
  }

  // final: out1 = sum over waves
  __syncthreads();
  sm.pbuf[w][2*lane]     = out1.x;
  sm.pbuf[w][2*lane + 1] = out1.y;
  __syncthreads();
  if (tid < 64) {
    float sx = 0.f, sy = 0.f;
    #pragma unroll
    for (int ww = 0; ww < 8; ++ww) {
      float2 v2 = *reinterpret_cast<const float2*>(&sm.pbuf[ww][2*tid]);
      sx += v2.x; sy += v2.y;
    }
    *reinterpret_cast<float2*>(out + (size_t)b * 256 + 2*tid) = make_float2(sx, sy);
  }
}

extern "C" void kernel_launch(void* const* d_in, const int* in_sizes, int n_in,
                              void* d_out, int out_size, void* d_ws, size_t ws_size,
                              hipStream_t stream) {
  (void)n_in; (void)d_ws; (void)ws_size; (void)out_size;
  const float* re    = (const float*)d_in[0];
  const int*   alias = (const int*)  d_in[1];
  const int*   slen  = (const int*)  d_in[2];
  const float* Wq    = (const float*)d_in[3];
  const float* Wk    = (const float*)d_in[4];
  const float* Wv    = (const float*)d_in[5];
  const float* uw1   = (const float*)d_in[6];
  const float* uw2   = (const float*)d_in[7];
  const float* ub    = (const float*)d_in[8];
  const float* uv    = (const float*)d_in[9];
  float* out = (float*)d_out;
  const int B = in_sizes[2];           // seq_len has B elements

  hipFuncSetAttribute(reinterpret_cast<const void*>(stamp_fused),
                      hipFuncAttributeMaxDynamicSharedMemorySize,
                      (int)sizeof(Smem));
  stamp_fused<<<B, 512, sizeof(Smem), stream>>>(re, alias, slen, Wq, Wk, Wv,
                                                uw1, uw2, ub, uv, out);
}

// Round 4
// 1064.989 us; speedup vs baseline: 6.2437x; 3.3418x over previous
//
#include <hip/hip_runtime.h>

// Fused STAMP session-attention, MFMA version. MI355X (gfx950).
// One block per batch (B=2048), 512 threads = 8 waves, 1 block/CU.
// All matmuls on v_mfma_f32_16x16x32_f16:
//   proj: K,V (all 16-row tiles) -> LDS (Kh row-major swizzled, VT transposed swizzled)
//   per q-tile (wave-independent, no barriers): Q-proj -> A-frags via LDS bounce,
//     flash attention over 32-col s-pairs (scores MFMA -> online softmax -> P
//     bounce -> PV MFMA), residual, seq_p MFMA, sigmoid/coef, out1 accum.
// Barriers: ~7 per block (vs ~90 in R3). Weights read from global as B-frags
// (L2/L3-hot, ~once per block). Rows t>=len provably dead -> skipped.

typedef _Float16 f16;
typedef _Float16 f16x8 __attribute__((ext_vector_type(8)));
typedef _Float16 f16x4 __attribute__((ext_vector_type(4)));
typedef float f32x4 __attribute__((ext_vector_type(4)));

#define MFMA(a,b,c) __builtin_amdgcn_mfma_f32_16x16x32_f16((a),(b),(c),0,0,0)

#define T_N   200
#define D_N   128
#define SCALE 0.08838834764831845f   // 1/sqrt(128)
#define FNEG  -3.0e38f

// ---- LDS byte map (total 160,576 <= 163,840) ----
#define OFF_KH   0        // Kh[208][128] f16, row stride 256 B, swz ((t&7)<<4)
#define OFF_VT   53248    // VT[128][256] f16, row stride 512 B, swz ((n&7)<<4)
#define OFF_SCR  118784   // per-wave scratch: 8 x 4096 ([16][128] f16, stride 256, swz)
#define OFF_AL   151552   // int   alias[208]
#define OFF_LP   152384   // float lastp[128]
#define OFF_DL   152896   // float declast[128]
#define OFF_UB   153408   // float ub[128]
#define OFF_UV   153920   // float uv[128]
#define OFF_LR   154432   // float lpred[4][128]
#define OFF_WR   156480   // float wred[8][128]
#define LDS_TOTAL 160576

// B-frag of W (row-major f32 [128][128]): lane(g,c) holds W[k0+8g+j][n], j=0..7
__device__ __forceinline__ f16x8 ld_w_frag(const float* __restrict__ W,
                                           int k0, int n, int g) {
  const float* p = W + (k0 + 8 * g) * D_N + n;
  f16x8 r;
  #pragma unroll
  for (int j = 0; j < 8; ++j) r[j] = (f16)p[j * D_N];
  return r;
}

// A-frag of X (gathered rows of re, f32): lane(g,c) holds X[t0+c][k0+8g+j]
__device__ __forceinline__ f16x8 ld_x_frag(const float* __restrict__ reb,
                                           const int* al, int t0, int k0,
                                           int g, int c) {
  const float* p = reb + (size_t)al[t0 + c] * D_N + k0 + 8 * g;
  float4 a = *(const float4*)p, b = *(const float4*)(p + 4);
  f16x8 r;
  r[0]=(f16)a.x; r[1]=(f16)a.y; r[2]=(f16)a.z; r[3]=(f16)a.w;
  r[4]=(f16)b.x; r[5]=(f16)b.y; r[6]=(f16)b.z; r[7]=(f16)b.w;
  return r;
}

// K,V projection for one 16-row tile -> Kh / VT (LDS, swizzled)
__device__ __forceinline__ void kvproj(char* smraw, const float* __restrict__ reb,
                                       const float* __restrict__ Wk,
                                       const float* __restrict__ Wv,
                                       int t0, int g, int c) {
  const int* al = (const int*)(smraw + OFF_AL);
  char* smK = smraw + OFF_KH;
  char* smV = smraw + OFF_VT;
  f16x8 xf[4];
  #pragma unroll
  for (int k0i = 0; k0i < 4; ++k0i) xf[k0i] = ld_x_frag(reb, al, t0, k0i << 5, g, c);
  #pragma unroll
  for (int n0i = 0; n0i < 8; ++n0i) {
    const int n = (n0i << 4) + c;
    f32x4 aK = {0.f,0.f,0.f,0.f}, aV = {0.f,0.f,0.f,0.f};
    #pragma unroll
    for (int k0i = 0; k0i < 4; ++k0i) {
      aK = MFMA(xf[k0i], ld_w_frag(Wk, k0i << 5, n, g), aK);
      aV = MFMA(xf[k0i], ld_w_frag(Wv, k0i << 5, n, g), aV);
    }
    #pragma unroll
    for (int r = 0; r < 4; ++r) {            // Kh[t][n], t = t0+4g+r
      const int t = t0 + (g << 2) + r;
      *(f16*)(smK + t * 256 + ((2 * n) ^ ((t & 7) << 4))) = (f16)fmaxf(aK[r], 0.f);
    }
    f16x4 pv;                                 // VT[n][t0+4g .. +3] (8B store)
    #pragma unroll
    for (int r = 0; r < 4; ++r) pv[r] = (f16)fmaxf(aV[r], 0.f);
    *(f16x4*)(smV + n * 512 + ((2 * (t0 + (g << 2))) ^ ((n & 7) << 4))) = pv;
  }
}

// One q-tile: Q-proj + flash attention + (STAMP ? stamp-epilogue : declast)
template <bool STAMP>
__device__ __forceinline__ void attention_tile(
    char* smraw, const float* __restrict__ reb,
    const float* __restrict__ Wq, const float* __restrict__ uw2,
    int t0, int len, int NS, int g, int c, int w,
    float* out1p /*[8]*/, int tlast) {
  const int* al = (const int*)(smraw + OFF_AL);
  char* scr = smraw + OFF_SCR + (w << 12);
  char* smK = smraw + OFF_KH;
  char* smV = smraw + OFF_VT;

  // ---- Q projection -> A-frags (via per-wave scratch bounce) ----
  f16x8 qf[4];
  {
    f16x8 xf[4];
    #pragma unroll
    for (int k0i = 0; k0i < 4; ++k0i) xf[k0i] = ld_x_frag(reb, al, t0, k0i << 5, g, c);
    #pragma unroll
    for (int n0i = 0; n0i < 8; ++n0i) {
      f32x4 acc = {0.f,0.f,0.f,0.f};
      #pragma unroll
      for (int k0i = 0; k0i < 4; ++k0i)
        acc = MFMA(xf[k0i], ld_w_frag(Wq, k0i << 5, (n0i << 4) + c, g), acc);
      #pragma unroll
      for (int r = 0; r < 4; ++r) {
        const int row = (g << 2) + r;
        *(f16*)(scr + row * 256 + ((2 * ((n0i << 4) + c)) ^ ((row & 7) << 4))) =
            (f16)fmaxf(acc[r], 0.f);
      }
    }
    #pragma unroll
    for (int k0i = 0; k0i < 4; ++k0i)
      qf[k0i] = *(const f16x8*)(scr + c * 256 +
                                ((2 * (k0i << 5) + 16 * g) ^ ((c & 7) << 4)));
  }

  // ---- flash attention over 32-col s-pairs ----
  f32x4 dacc[8];
  #pragma unroll
  for (int i = 0; i < 8; ++i) dacc[i] = f32x4{0.f,0.f,0.f,0.f};
  float m_run[4] = {FNEG, FNEG, FNEG, FNEG};
  float l_run[4] = {0.f, 0.f, 0.f, 0.f};
  const int npair = (NS + 1) >> 1;

  for (int p = 0; p < npair; ++p) {
    const int s0 = p << 5;
    const bool hasB = (2 * p + 1) < NS;
    f32x4 sA = {0.f,0.f,0.f,0.f}, sB = {0.f,0.f,0.f,0.f};
    {
      const int sa = s0 + c;
      const int swa = (sa & 7) << 4;
      #pragma unroll
      for (int k0i = 0; k0i < 4; ++k0i)
        sA = MFMA(qf[k0i],
                  *(const f16x8*)(smK + sa * 256 + ((2*(k0i<<5) + 16*g) ^ swa)), sA);
    }
    if (hasB) {
      const int sb = s0 + 16 + c;
      const int swb = (sb & 7) << 4;
      #pragma unroll
      for (int k0i = 0; k0i < 4; ++k0i)
        sB = MFMA(qf[k0i],
                  *(const f16x8*)(smK + sb * 256 + ((2*(k0i<<5) + 16*g) ^ swb)), sB);
    }
    float corr[4];
    #pragma unroll
    for (int r = 0; r < 4; ++r) {
      float a  = (s0 + c < len)                ? sA[r] * SCALE : FNEG;
      float bq = (hasB && (s0 + 16 + c < len)) ? sB[r] * SCALE : FNEG;
      float mx = fmaxf(a, bq);
      mx = fmaxf(mx, __shfl_xor(mx, 1, 64));
      mx = fmaxf(mx, __shfl_xor(mx, 2, 64));
      mx = fmaxf(mx, __shfl_xor(mx, 4, 64));
      mx = fmaxf(mx, __shfl_xor(mx, 8, 64));
      const float mnew = fmaxf(m_run[r], mx);
      const float cr = __expf(m_run[r] - mnew);
      const float pa = __expf(a - mnew);
      const float pb = __expf(bq - mnew);
      float rs = pa + pb;
      rs += __shfl_xor(rs, 1, 64); rs += __shfl_xor(rs, 2, 64);
      rs += __shfl_xor(rs, 4, 64); rs += __shfl_xor(rs, 8, 64);
      l_run[r] = l_run[r] * cr + rs;
      m_run[r] = mnew; corr[r] = cr;
      const int row = (g << 2) + r;              // P -> scratch (D->A bounce)
      char* rb = scr + row * 256;
      const int sw = (row & 7) << 4;
      *(f16*)(rb + ((2 * c) ^ sw))        = (f16)pa;
      *(f16*)(rb + ((2 * (16 + c)) ^ sw)) = (f16)pb;
    }
    #pragma unroll
    for (int i = 0; i < 8; ++i) {
      dacc[i][0] *= corr[0]; dacc[i][1] *= corr[1];
      dacc[i][2] *= corr[2]; dacc[i][3] *= corr[3];
    }
    f16x8 pf = *(const f16x8*)(scr + c * 256 + ((16 * g) ^ ((c & 7) << 4)));
    #pragma unroll
    for (int n0i = 0; n0i < 8; ++n0i) {
      const int n = (n0i << 4) + c;
      f16x8 vf = *(const f16x8*)(smV + n * 512 + ((2 * s0 + 16 * g) ^ ((n & 7) << 4)));
      dacc[n0i] = MFMA(pf, vf, dacc[n0i]);
    }
  }

  // ---- finalize: normalize + residual (f32 from global) ----
  float rl[4];
  #pragma unroll
  for (int r = 0; r < 4; ++r) rl[r] = 1.0f / l_run[r];
  #pragma unroll
  for (int n0i = 0; n0i < 8; ++n0i) {
    #pragma unroll
    for (int r = 0; r < 4; ++r) {
      const int t = t0 + (g << 2) + r;
      const float xv = reb[(size_t)al[t] * D_N + (n0i << 4) + c];
      dacc[n0i][r] = dacc[n0i][r] * rl[r] + xv;
    }
  }

  if (!STAMP) {                                // pass0: emit dec[len-1] row
    float* dl = (float*)(smraw + OFF_DL);
    const int rho = tlast & 15;
    if ((rho >> 2) == g) {
      const int r0 = rho & 3;
      #pragma unroll
      for (int n0i = 0; n0i < 8; ++n0i) {
        const float v = (r0 == 0) ? dacc[n0i][0] : (r0 == 1) ? dacc[n0i][1]
                      : (r0 == 2) ? dacc[n0i][2] : dacc[n0i][3];
        dl[(n0i << 4) + c] = v;
      }
    }
    return;
  }

  // ---- STAMP: seq_p = dec @ u_w2 (MFMA via bounce), sigmoid, coef, out1 ----
  #pragma unroll
  for (int n0i = 0; n0i < 8; ++n0i) {
    #pragma unroll
    for (int r = 0; r < 4; ++r) {
      const int row = (g << 2) + r;
      *(f16*)(scr + row * 256 + ((2 * ((n0i << 4) + c)) ^ ((row & 7) << 4))) =
          (f16)dacc[n0i][r];
    }
  }
  f16x8 da[4];
  #pragma unroll
  for (int k0i = 0; k0i < 4; ++k0i)
    da[k0i] = *(const f16x8*)(scr + c * 256 +
                              ((2 * (k0i << 5) + 16 * g) ^ ((c & 7) << 4)));
  const float* lp  = (const float*)(smraw + OFF_LP);
  const float* ubp = (const float*)(smraw + OFF_UB);
  const float* uvp = (const float*)(smraw + OFF_UV);
  float cs[4] = {0.f, 0.f, 0.f, 0.f};
  #pragma unroll
  for (int n0i = 0; n0i < 8; ++n0i) {
    f32x4 sp = {0.f,0.f,0.f,0.f};
    #pragma unroll
    for (int k0i = 0; k0i < 4; ++k0i)
      sp = MFMA(da[k0i], ld_w_frag(uw2, k0i << 5, (n0i << 4) + c, g), sp);
    const int n = (n0i << 4) + c;
    const float add = lp[n] + ubp[n];
    const float uvn = uvp[n];
    #pragma unroll
    for (int r = 0; r < 4; ++r) {
      const float sig = 1.0f / (1.0f + __expf(-(sp[r] + add)));
      cs[r] += sig * uvn;
    }
  }
  #pragma unroll
  for (int r = 0; r < 4; ++r) {
    float cf = cs[r];
    cf += __shfl_xor(cf, 1, 64); cf += __shfl_xor(cf, 2, 64);
    cf += __shfl_xor(cf, 4, 64); cf += __shfl_xor(cf, 8, 64);
    const int t = t0 + (g << 2) + r;
    cf = (t < len) ? cf : 0.f;
    #pragma unroll
    for (int n0i = 0; n0i < 8; ++n0i) out1p[n0i] += cf * dacc[n0i][r];
  }
}

__global__ __launch_bounds__(512, 2)
void stamp_mfma(const float* __restrict__ re, const int* __restrict__ aliasg,
                const int* __restrict__ slen,
                const float* __restrict__ Wq, const float* __restrict__ Wk,
                const float* __restrict__ Wv, const float* __restrict__ uw1,
                const float* __restrict__ uw2, const float* __restrict__ ub,
                const float* __restrict__ uv, float* __restrict__ out) {
  extern __shared__ char smraw[];
  const int tid  = threadIdx.x;
  const int lane = tid & 63;
  const int w    = tid >> 6;
  const int g    = lane >> 4;
  const int c    = lane & 15;
  const int b    = blockIdx.x;
  const int len  = slen[b];
  const int NS    = (len + 15) >> 4;            // 16-tiles covering [0,len)
  const int NPROJ = (NS + (NS & 1) < 13) ? NS + (NS & 1) : 13;
  const int tlast = len - 1;
  const float* __restrict__ reb = re + (size_t)b * (T_N * D_N);

  // ---- init LDS ----
  if (tid < 208) ((int*)(smraw + OFF_AL))[tid] = (tid < T_N) ? aliasg[b * T_N + tid] : 0;
  if (tid < 128) {
    ((float*)(smraw + OFF_UB))[tid] = ub[tid];
    ((float*)(smraw + OFF_UV))[tid] = uv[tid];
    // zero VT cols [208,224) (tail PV B-frags may touch them)
    f16x8 z = {};
    char* vrow = smraw + OFF_VT + tid * 512;
    const int sw = (tid & 7) << 4;
    *(f16x8*)(vrow + (416 ^ sw)) = z;
    *(f16x8*)(vrow + (432 ^ sw)) = z;
  }
  __syncthreads();

  // ---- K,V projections (tiles split across waves) ----
  for (int mt = w; mt < NPROJ; mt += 8) kvproj(smraw, reb, Wk, Wv, mt << 4, g, c);
  __syncthreads();                              // Kh, VT complete

  // ---- pass0: dec[len-1] -> declast ----
  const int TL = tlast >> 4;
  if (w == (TL & 7))
    attention_tile<false>(smraw, reb, Wq, uw2, TL << 4, len, NS, g, c, w, nullptr, tlast);
  __syncthreads();

  // ---- lastp = declast @ u_w1 (cooperative), emit out[:,128:256] ----
  {
    const int j = tid & 127, seg = tid >> 7;
    const float* dl = (const float*)(smraw + OFF_DL);
    float acc = 0.f;
    for (int i = 0; i < 32; ++i) {
      const int d = (seg << 5) + i;
      acc += dl[d] * uw1[d * D_N + j];
    }
    ((float*)(smraw + OFF_LR))[(seg << 7) + j] = acc;
  }
  __syncthreads();
  if (tid < 128) {
    const float* lr = (const float*)(smraw + OFF_LR);
    const float v = lr[tid] + lr[128 + tid] + lr[256 + tid] + lr[384 + tid];
    ((float*)(smraw + OFF_LP))[tid] = v;
    out[(size_t)b * 256 + 128 + tid] = v;
  }
  __syncthreads();                              // lastp visible

  // ---- pass1: all q-tiles, wave-independent ----
  float out1p[8] = {0.f,0.f,0.f,0.f,0.f,0.f,0.f,0.f};
  for (int qt = w; qt < NS; qt += 8)
    attention_tile<true>(smraw, reb, Wq, uw2, qt << 4, len, NS, g, c, w, out1p, tlast);

  // ---- out1 reduction ----
  #pragma unroll
  for (int i = 0; i < 8; ++i) {
    out1p[i] += __shfl_xor(out1p[i], 16, 64);
    out1p[i] += __shfl_xor(out1p[i], 32, 64);
  }
  float* wr = (float*)(smraw + OFF_WR) + (w << 7);
  if (g == 0) {
    #pragma unroll
    for (int i = 0; i < 8; ++i) wr[(i << 4) + c] = out1p[i];
  }
  __syncthreads();
  if (tid < 128) {
    const float* wrb = (const float*)(smraw + OFF_WR);
    float s = 0.f;
    #pragma unroll
    for (int ww = 0; ww < 8; ++ww) s += wrb[(ww << 7) + tid];
    out[(size_t)b * 256 + tid] = s;
  }
}

extern "C" void kernel_launch(void* const* d_in, const int* in_sizes, int n_in,
                              void* d_out, int out_size, void* d_ws, size_t ws_size,
                              hipStream_t stream) {
  (void)n_in; (void)d_ws; (void)ws_size; (void)out_size;
  const float* re    = (const float*)d_in[0];
  const int*   alias = (const int*)  d_in[1];
  const int*   slen  = (const int*)  d_in[2];
  const float* Wq    = (const float*)d_in[3];
  const float* Wk    = (const float*)d_in[4];
  const float* Wv    = (const float*)d_in[5];
  const float* uw1   = (const float*)d_in[6];
  const float* uw2   = (const float*)d_in[7];
  const float* ub    = (const float*)d_in[8];
  const float* uv    = (const float*)d_in[9];
  float* out = (float*)d_out;
  const int B = in_sizes[2];

  hipFuncSetAttribute(reinterpret_cast<const void*>(stamp_mfma),
                      hipFuncAttributeMaxDynamicSharedMemorySize, LDS_TOTAL);
  stamp_mfma<<<B, 512, LDS_TOTAL, stream>>>(re, alias, slen, Wq, Wk, Wv,
                                            uw1, uw2, ub, uv, out);
}

// Round 5
// 868.221 us; speedup vs baseline: 7.6587x; 1.2266x over previous
//
#include <hip/hip_runtime.h>

// Fused STAMP session-attention, MFMA version, R5. MI355X (gfx950).
// One block per batch (B=2048), 512 threads = 8 waves, 1 block/CU.
// R5 changes vs R4 (spill + weight-load latency fix; counters: WRITE_SIZE
// 763MB = scratch spill at VGPR=128 = 4-waves/EU target; 8x stride-512B
// weight loads per B-frag):
//   1) amdgpu_waves_per_eu(2,2): VGPR budget 256 (LDS caps at 2 waves/SIMD
//      anyway) -> no spill.
//   2) pack_w prep kernel: Wq/Wk/Wv/u_w2 -> f16 B-frag-linear layout in d_ws;
//      each weight fragment = one coalesced 16B/lane load (L2/L3-hot).
// Attention core (verified R4) unchanged.

typedef _Float16 f16;
typedef _Float16 f16x8 __attribute__((ext_vector_type(8)));
typedef _Float16 f16x4 __attribute__((ext_vector_type(4)));
typedef float f32x4 __attribute__((ext_vector_type(4)));

#define MFMA(a,b,c) __builtin_amdgcn_mfma_f32_16x16x32_f16((a),(b),(c),0,0,0)

#define T_N   200
#define D_N   128
#define SCALE 0.08838834764831845f   // 1/sqrt(128)
#define FNEG  -3.0e38f

// ---- LDS byte map (total 160,576 <= 163,840) ----
#define OFF_KH   0        // Kh[208][128] f16, row stride 256 B, swz ((t&7)<<4)
#define OFF_VT   53248    // VT[128][256] f16, row stride 512 B, swz ((n&7)<<4)
#define OFF_SCR  118784   // per-wave scratch: 8 x 4096 ([16][128] f16, stride 256, swz)
#define OFF_AL   151552   // int   alias[208]
#define OFF_LP   152384   // float lastp[128]
#define OFF_DL   152896   // float declast[128]
#define OFF_UB   153408   // float ub[128]
#define OFF_UV   153920   // float uv[128]
#define OFF_LR   154432   // float lpred[4][128]
#define OFF_WR   156480   // float wred[8][128]
#define LDS_TOTAL 160576

// matrix ids in packed weight buffer
#define MAT_WQ 0
#define MAT_WK 1
#define MAT_WV 2
#define MAT_W2 3

// ---- prep kernel: pack W (f32 row-major [128][128]) into B-frag-linear f16 ----
// frag (k0i 0..3, n0i 0..7); lane l=(g,c) holds W[k0i*32+8g+j][n0i*16+c], j=0..7
// flat f16 index: ((mat*32 + k0i*8 + n0i)*64 + l)*8 + j
__global__ __launch_bounds__(256)
void pack_w(const float* __restrict__ Wq, const float* __restrict__ Wk,
            const float* __restrict__ Wv, const float* __restrict__ uw2,
            f16* __restrict__ pw) {
  const int m   = blockIdx.x * 256 + threadIdx.x;   // 0..8191
  const int mat = m >> 11;
  const int f   = (m >> 6) & 31;
  const int l   = m & 63;
  const int g = l >> 4, c = l & 15;
  const int k0i = f >> 3, n0i = f & 7;
  const float* W = (mat == 0) ? Wq : (mat == 1) ? Wk : (mat == 2) ? Wv : uw2;
  const float* p = W + (k0i * 32 + 8 * g) * D_N + n0i * 16 + c;
  f16x8 r;
  #pragma unroll
  for (int j = 0; j < 8; ++j) r[j] = (f16)p[j * D_N];
  *(f16x8*)(pw + (size_t)m * 8) = r;
}

// B-frag of W: packed (one dwordx4) or strided-gather fallback
__device__ __forceinline__ f16x8 ld_w_strided(const float* __restrict__ W,
                                              int k0, int n, int g) {
  const float* p = W + (k0 + 8 * g) * D_N + n;
  f16x8 r;
  #pragma unroll
  for (int j = 0; j < 8; ++j) r[j] = (f16)p[j * D_N];
  return r;
}
template <bool PACKED>
__device__ __forceinline__ f16x8 wfrag(const f16* __restrict__ pw, int mat,
                                       const float* __restrict__ W,
                                       int k0i, int n0i, int g, int c) {
  if constexpr (PACKED) {
    const int lane = (g << 4) + c;
    return *(const f16x8*)(pw + (size_t)((((mat << 5) + (k0i << 3) + n0i) << 6) + lane) * 8);
  } else {
    return ld_w_strided(W, k0i << 5, (n0i << 4) + c, g);
  }
}

// A-frag of X (gathered rows of re, f32): lane(g,c) holds X[t0+c][k0+8g+j]
__device__ __forceinline__ f16x8 ld_x_frag(const float* __restrict__ reb,
                                           const int* al, int t0, int k0,
                                           int g, int c) {
  const float* p = reb + (size_t)al[t0 + c] * D_N + k0 + 8 * g;
  float4 a = *(const float4*)p, b = *(const float4*)(p + 4);
  f16x8 r;
  r[0]=(f16)a.x; r[1]=(f16)a.y; r[2]=(f16)a.z; r[3]=(f16)a.w;
  r[4]=(f16)b.x; r[5]=(f16)b.y; r[6]=(f16)b.z; r[7]=(f16)b.w;
  return r;
}

// K,V projection for one 16-row tile -> Kh / VT (LDS, swizzled)
template <bool PACKED>
__device__ __forceinline__ void kvproj(char* smraw, const float* __restrict__ reb,
                                       const float* __restrict__ Wk,
                                       const float* __restrict__ Wv,
                                       const f16* __restrict__ pw,
                                       int t0, int g, int c) {
  const int* al = (const int*)(smraw + OFF_AL);
  char* smK = smraw + OFF_KH;
  char* smV = smraw + OFF_VT;
  f16x8 xf[4];
  #pragma unroll
  for (int k0i = 0; k0i < 4; ++k0i) xf[k0i] = ld_x_frag(reb, al, t0, k0i << 5, g, c);
  #pragma unroll
  for (int n0i = 0; n0i < 8; ++n0i) {
    const int n = (n0i << 4) + c;
    f32x4 aK = {0.f,0.f,0.f,0.f}, aV = {0.f,0.f,0.f,0.f};
    #pragma unroll
    for (int k0i = 0; k0i < 4; ++k0i) {
      aK = MFMA(xf[k0i], wfrag<PACKED>(pw, MAT_WK, Wk, k0i, n0i, g, c), aK);
      aV = MFMA(xf[k0i], wfrag<PACKED>(pw, MAT_WV, Wv, k0i, n0i, g, c), aV);
    }
    #pragma unroll
    for (int r = 0; r < 4; ++r) {            // Kh[t][n], t = t0+4g+r
      const int t = t0 + (g << 2) + r;
      *(f16*)(smK + t * 256 + ((2 * n) ^ ((t & 7) << 4))) = (f16)fmaxf(aK[r], 0.f);
    }
    f16x4 pv;                                 // VT[n][t0+4g .. +3] (8B store)
    #pragma unroll
    for (int r = 0; r < 4; ++r) pv[r] = (f16)fmaxf(aV[r], 0.f);
    *(f16x4*)(smV + n * 512 + ((2 * (t0 + (g << 2))) ^ ((n & 7) << 4))) = pv;
  }
}

// One q-tile: Q-proj + flash attention + (STAMP ? stamp-epilogue : declast)
template <bool STAMP, bool PACKED>
__device__ __forceinline__ void attention_tile(
    char* smraw, const float* __restrict__ reb,
    const float* __restrict__ Wq, const float* __restrict__ uw2,
    const f16* __restrict__ pw,
    int t0, int len, int NS, int g, int c, int w,
    float (&out1p)[8], int tlast) {
  const int* al = (const int*)(smraw + OFF_AL);
  char* scr = smraw + OFF_SCR + (w << 12);
  char* smK = smraw + OFF_KH;
  char* smV = smraw + OFF_VT;

  // ---- Q projection -> A-frags (via per-wave scratch bounce) ----
  f16x8 qf[4];
  {
    f16x8 xf[4];
    #pragma unroll
    for (int k0i = 0; k0i < 4; ++k0i) xf[k0i] = ld_x_frag(reb, al, t0, k0i << 5, g, c);
    #pragma unroll
    for (int n0i = 0; n0i < 8; ++n0i) {
      f32x4 acc = {0.f,0.f,0.f,0.f};
      #pragma unroll
      for (int k0i = 0; k0i < 4; ++k0i)
        acc = MFMA(xf[k0i], wfrag<PACKED>(pw, MAT_WQ, Wq, k0i, n0i, g, c), acc);
      #pragma unroll
      for (int r = 0; r < 4; ++r) {
        const int row = (g << 2) + r;
        *(f16*)(scr + row * 256 + ((2 * ((n0i << 4) + c)) ^ ((row & 7) << 4))) =
            (f16)fmaxf(acc[r], 0.f);
      }
    }
    #pragma unroll
    for (int k0i = 0; k0i < 4; ++k0i)
      qf[k0i] = *(const f16x8*)(scr + c * 256 +
                                ((2 * (k0i << 5) + 16 * g) ^ ((c & 7) << 4)));
  }

  // ---- flash attention over 32-col s-pairs ----
  f32x4 dacc[8];
  #pragma unroll
  for (int i = 0; i < 8; ++i) dacc[i] = f32x4{0.f,0.f,0.f,0.f};
  float m_run[4] = {FNEG, FNEG, FNEG, FNEG};
  float l_run[4] = {0.f, 0.f, 0.f, 0.f};
  const int npair = (NS + 1) >> 1;

  for (int p = 0; p < npair; ++p) {
    const int s0 = p << 5;
    const bool hasB = (2 * p + 1) < NS;
    f32x4 sA = {0.f,0.f,0.f,0.f}, sB = {0.f,0.f,0.f,0.f};
    {
      const int sa = s0 + c;
      const int swa = (sa & 7) << 4;
      #pragma unroll
      for (int k0i = 0; k0i < 4; ++k0i)
        sA = MFMA(qf[k0i],
                  *(const f16x8*)(smK + sa * 256 + ((2*(k0i<<5) + 16*g) ^ swa)), sA);
    }
    if (hasB) {
      const int sb = s0 + 16 + c;
      const int swb = (sb & 7) << 4;
      #pragma unroll
      for (int k0i = 0; k0i < 4; ++k0i)
        sB = MFMA(qf[k0i],
                  *(const f16x8*)(smK + sb * 256 + ((2*(k0i<<5) + 16*g) ^ swb)), sB);
    }
    float corr[4];
    #pragma unroll
    for (int r = 0; r < 4; ++r) {
      float a  = (s0 + c < len)                ? sA[r] * SCALE : FNEG;
      float bq = (hasB && (s0 + 16 + c < len)) ? sB[r] * SCALE : FNEG;
      float mx = fmaxf(a, bq);
      mx = fmaxf(mx, __shfl_xor(mx, 1, 64));
      mx = fmaxf(mx, __shfl_xor(mx, 2, 64));
      mx = fmaxf(mx, __shfl_xor(mx, 4, 64));
      mx = fmaxf(mx, __shfl_xor(mx, 8, 64));
      const float mnew = fmaxf(m_run[r], mx);
      const float cr = __expf(m_run[r] - mnew);
      const float pa = __expf(a - mnew);
      const float pb = __expf(bq - mnew);
      float rs = pa + pb;
      rs += __shfl_xor(rs, 1, 64); rs += __shfl_xor(rs, 2, 64);
      rs += __shfl_xor(rs, 4, 64); rs += __shfl_xor(rs, 8, 64);
      l_run[r] = l_run[r] * cr + rs;
      m_run[r] = mnew; corr[r] = cr;
      const int row = (g << 2) + r;              // P -> scratch (D->A bounce)
      char* rb = scr + row * 256;
      const int sw = (row & 7) << 4;
      *(f16*)(rb + ((2 * c) ^ sw))        = (f16)pa;
      *(f16*)(rb + ((2 * (16 + c)) ^ sw)) = (f16)pb;
    }
    #pragma unroll
    for (int i = 0; i < 8; ++i) {
      dacc[i][0] *= corr[0]; dacc[i][1] *= corr[1];
      dacc[i][2] *= corr[2]; dacc[i][3] *= corr[3];
    }
    f16x8 pf = *(const f16x8*)(scr + c * 256 + ((16 * g) ^ ((c & 7) << 4)));
    #pragma unroll
    for (int n0i = 0; n0i < 8; ++n0i) {
      const int n = (n0i << 4) + c;
      f16x8 vf = *(const f16x8*)(smV + n * 512 + ((2 * s0 + 16 * g) ^ ((n & 7) << 4)));
      dacc[n0i] = MFMA(pf, vf, dacc[n0i]);
    }
  }

  // ---- finalize: normalize + residual (f32 from global) ----
  float rl[4];
  #pragma unroll
  for (int r = 0; r < 4; ++r) rl[r] = 1.0f / l_run[r];
  #pragma unroll
  for (int n0i = 0; n0i < 8; ++n0i) {
    #pragma unroll
    for (int r = 0; r < 4; ++r) {
      const int t = t0 + (g << 2) + r;
      const float xv = reb[(size_t)al[t] * D_N + (n0i << 4) + c];
      dacc[n0i][r] = dacc[n0i][r] * rl[r] + xv;
    }
  }

  if (!STAMP) {                                // pass0: emit dec[len-1] row
    float* dl = (float*)(smraw + OFF_DL);
    const int rho = tlast & 15;
    if ((rho >> 2) == g) {
      const int r0 = rho & 3;
      #pragma unroll
      for (int n0i = 0; n0i < 8; ++n0i) {
        const float v = (r0 == 0) ? dacc[n0i][0] : (r0 == 1) ? dacc[n0i][1]
                      : (r0 == 2) ? dacc[n0i][2] : dacc[n0i][3];
        dl[(n0i << 4) + c] = v;
      }
    }
    return;
  }

  // ---- STAMP: seq_p = dec @ u_w2 (MFMA via bounce), sigmoid, coef, out1 ----
  #pragma unroll
  for (int n0i = 0; n0i < 8; ++n0i) {
    #pragma unroll
    for (int r = 0; r < 4; ++r) {
      const int row = (g << 2) + r;
      *(f16*)(scr + row * 256 + ((2 * ((n0i << 4) + c)) ^ ((row & 7) << 4))) =
          (f16)dacc[n0i][r];
    }
  }
  f16x8 da[4];
  #pragma unroll
  for (int k0i = 0; k0i < 4; ++k0i)
    da[k0i] = *(const f16x8*)(scr + c * 256 +
                              ((2 * (k0i << 5) + 16 * g) ^ ((c & 7) << 4)));
  const float* lp  = (const float*)(smraw + OFF_LP);
  const float* ubp = (const float*)(smraw + OFF_UB);
  const float* uvp = (const float*)(smraw + OFF_UV);
  float cs[4] = {0.f, 0.f, 0.f, 0.f};
  #pragma unroll
  for (int n0i = 0; n0i < 8; ++n0i) {
    f32x4 sp = {0.f,0.f,0.f,0.f};
    #pragma unroll
    for (int k0i = 0; k0i < 4; ++k0i)
      sp = MFMA(da[k0i], wfrag<PACKED>(pw, MAT_W2, uw2, k0i, n0i, g, c), sp);
    const int n = (n0i << 4) + c;
    const float add = lp[n] + ubp[n];
    const float uvn = uvp[n];
    #pragma unroll
    for (int r = 0; r < 4; ++r) {
      const float sig = 1.0f / (1.0f + __expf(-(sp[r] + add)));
      cs[r] += sig * uvn;
    }
  }
  #pragma unroll
  for (int r = 0; r < 4; ++r) {
    float cf = cs[r];
    cf += __shfl_xor(cf, 1, 64); cf += __shfl_xor(cf, 2, 64);
    cf += __shfl_xor(cf, 4, 64); cf += __shfl_xor(cf, 8, 64);
    const int t = t0 + (g << 2) + r;
    cf = (t < len) ? cf : 0.f;
    #pragma unroll
    for (int n0i = 0; n0i < 8; ++n0i) out1p[n0i] += cf * dacc[n0i][r];
  }
}

template <bool PACKED>
__global__ __launch_bounds__(512)
__attribute__((amdgpu_waves_per_eu(2, 2)))   // VGPR budget 256; LDS caps at 2 waves/SIMD anyway
void stamp_mfma(const float* __restrict__ re, const int* __restrict__ aliasg,
                const int* __restrict__ slen,
                const float* __restrict__ Wq, const float* __restrict__ Wk,
                const float* __restrict__ Wv, const float* __restrict__ uw1,
                const float* __restrict__ uw2, const float* __restrict__ ub,
                const float* __restrict__ uv, const f16* __restrict__ pw,
                float* __restrict__ out) {
  extern __shared__ char smraw[];
  const int tid  = threadIdx.x;
  const int lane = tid & 63;
  const int w    = tid >> 6;
  const int g    = lane >> 4;
  const int c    = lane & 15;
  const int b    = blockIdx.x;
  const int len  = slen[b];
  const int NS    = (len + 15) >> 4;            // 16-tiles covering [0,len)
  const int NPROJ = (NS + (NS & 1) < 13) ? NS + (NS & 1) : 13;
  const int tlast = len - 1;
  const float* __restrict__ reb = re + (size_t)b * (T_N * D_N);

  // ---- init LDS ----
  if (tid < 208) ((int*)(smraw + OFF_AL))[tid] = (tid < T_N) ? aliasg[b * T_N + tid] : 0;
  if (tid < 128) {
    ((float*)(smraw + OFF_UB))[tid] = ub[tid];
    ((float*)(smraw + OFF_UV))[tid] = uv[tid];
    // zero VT cols [208,224) (tail PV B-frags may touch them)
    f16x8 z = {};
    char* vrow = smraw + OFF_VT + tid * 512;
    const int sw = (tid & 7) << 4;
    *(f16x8*)(vrow + (416 ^ sw)) = z;
    *(f16x8*)(vrow + (432 ^ sw)) = z;
  }
  __syncthreads();

  // ---- K,V projections (tiles split across waves) ----
  for (int mt = w; mt < NPROJ; mt += 8)
    kvproj<PACKED>(smraw, reb, Wk, Wv, pw, mt << 4, g, c);
  __syncthreads();                              // Kh, VT complete

  // ---- pass0: dec[len-1] -> declast ----
  float dummy[8] = {0,0,0,0,0,0,0,0};
  const int TL = tlast >> 4;
  if (w == (TL & 7))
    attention_tile<false, PACKED>(smraw, reb, Wq, uw2, pw, TL << 4, len, NS,
                                  g, c, w, dummy, tlast);
  __syncthreads();

  // ---- lastp = declast @ u_w1 (cooperative), emit out[:,128:256] ----
  {
    const int j = tid & 127, seg = tid >> 7;
    const float* dl = (const float*)(smraw + OFF_DL);
    float acc = 0.f;
    for (int i = 0; i < 32; ++i) {
      const int d = (seg << 5) + i;
      acc += dl[d] * uw1[d * D_N + j];
    }
    ((float*)(smraw + OFF_LR))[(seg << 7) + j] = acc;
  }
  __syncthreads();
  if (tid < 128) {
    const float* lr = (const float*)(smraw + OFF_LR);
    const float v = lr[tid] + lr[128 + tid] + lr[256 + tid] + lr[384 + tid];
    ((float*)(smraw + OFF_LP))[tid] = v;
    out[(size_t)b * 256 + 128 + tid] = v;
  }
  __syncthreads();                              // lastp visible

  // ---- pass1: all q-tiles, wave-independent ----
  float out1p[8] = {0.f,0.f,0.f,0.f,0.f,0.f,0.f,0.f};
  for (int qt = w; qt < NS; qt += 8)
    attention_tile<true, PACKED>(smraw, reb, Wq, uw2, pw, qt << 4, len, NS,
                                 g, c, w, out1p, tlast);

  // ---- out1 reduction ----
  #pragma unroll
  for (int i = 0; i < 8; ++i) {
    out1p[i] += __shfl_xor(out1p[i], 16, 64);
    out1p[i] += __shfl_xor(out1p[i], 32, 64);
  }
  float* wr = (float*)(smraw + OFF_WR) + (w << 7);
  if (g == 0) {
    #pragma unroll
    for (int i = 0; i < 8; ++i) wr[(i << 4) + c] = out1p[i];
  }
  __syncthreads();
  if (tid < 128) {
    const float* wrb = (const float*)(smraw + OFF_WR);
    float s = 0.f;
    #pragma unroll
    for (int ww = 0; ww < 8; ++ww) s += wrb[(ww << 7) + tid];
    out[(size_t)b * 256 + tid] = s;
  }
}

extern "C" void kernel_launch(void* const* d_in, const int* in_sizes, int n_in,
                              void* d_out, int out_size, void* d_ws, size_t ws_size,
                              hipStream_t stream) {
  (void)n_in; (void)out_size;
  const float* re    = (const float*)d_in[0];
  const int*   alias = (const int*)  d_in[1];
  const int*   slen  = (const int*)  d_in[2];
  const float* Wq    = (const float*)d_in[3];
  const float* Wk    = (const float*)d_in[4];
  const float* Wv    = (const float*)d_in[5];
  const float* uw1   = (const float*)d_in[6];
  const float* uw2   = (const float*)d_in[7];
  const float* ub    = (const float*)d_in[8];
  const float* uv    = (const float*)d_in[9];
  float* out = (float*)d_out;
  const int B = in_sizes[2];

  const bool packed = (d_ws != nullptr) && (ws_size >= 4 * 16384 * sizeof(f16));
  if (packed) {
    f16* pw = (f16*)d_ws;
    pack_w<<<32, 256, 0, stream>>>(Wq, Wk, Wv, uw2, pw);
    hipFuncSetAttribute(reinterpret_cast<const void*>(&stamp_mfma<true>),
                        hipFuncAttributeMaxDynamicSharedMemorySize, LDS_TOTAL);
    stamp_mfma<true><<<B, 512, LDS_TOTAL, stream>>>(
        re, alias, slen, Wq, Wk, Wv, uw1, uw2, ub, uv, pw, out);
  } else {
    hipFuncSetAttribute(reinterpret_cast<const void*>(&stamp_mfma<false>),
                        hipFuncAttributeMaxDynamicSharedMemorySize, LDS_TOTAL);
    stamp_mfma<false><<<B, 512, LDS_TOTAL, stream>>>(
        re, alias, slen, Wq, Wk, Wv, uw1, uw2, ub, uv, nullptr, out);
  }
}

// Round 6
// 538.783 us; speedup vs baseline: 12.3416x; 1.6114x over previous
//
#include <hip/hip_runtime.h>

// Fused STAMP session-attention, MFMA version, R6. MI355X (gfx950).
// One block per batch (B=2048), 512 threads = 8 waves, 1 block/CU.
// R6 changes vs R5 (kill the 733MB/dispatch scratch-spill traffic):
//   1) non-template kernel (waves_per_eu attribute reliably applied; no
//      co-compiled sibling instantiation perturbing regalloc)
//   2) #pragma unroll 2 on the three weight-consuming n0i loops: <=16
//      weight-frag loads in flight (64 VGPR) instead of 128+ -> peak
//      pressure fits the budget, no spill.
// Weights always consumed via pw (B-frag-packed f16 in d_ws by pack_w).
// Attention core (verified R4/R5) unchanged.

typedef _Float16 f16;
typedef _Float16 f16x8 __attribute__((ext_vector_type(8)));
typedef _Float16 f16x4 __attribute__((ext_vector_type(4)));
typedef float f32x4 __attribute__((ext_vector_type(4)));

#define MFMA(a,b,c) __builtin_amdgcn_mfma_f32_16x16x32_f16((a),(b),(c),0,0,0)

#define T_N   200
#define D_N   128
#define SCALE 0.08838834764831845f   // 1/sqrt(128)
#define FNEG  -3.0e38f

// ---- LDS byte map (total 160,576 <= 163,840) ----
#define OFF_KH   0        // Kh[208][128] f16, row stride 256 B, swz ((t&7)<<4)
#define OFF_VT   53248    // VT[128][256] f16, row stride 512 B, swz ((n&7)<<4)
#define OFF_SCR  118784   // per-wave scratch: 8 x 4096 ([16][128] f16, stride 256, swz)
#define OFF_AL   151552   // int   alias[208]
#define OFF_LP   152384   // float lastp[128]
#define OFF_DL   152896   // float declast[128]
#define OFF_UB   153408   // float ub[128]
#define OFF_UV   153920   // float uv[128]
#define OFF_LR   154432   // float lpred[4][128]
#define OFF_WR   156480   // float wred[8][128]
#define LDS_TOTAL 160576

// matrix ids in packed weight buffer
#define MAT_WQ 0
#define MAT_WK 1
#define MAT_WV 2
#define MAT_W2 3

// ---- prep kernel: pack W (f32 row-major [128][128]) into B-frag-linear f16 ----
// frag (k0i 0..3, n0i 0..7); lane l=(g,c) holds W[k0i*32+8g+j][n0i*16+c], j=0..7
// flat f16 index: ((mat*32 + k0i*8 + n0i)*64 + l)*8 + j
__global__ __launch_bounds__(256)
void pack_w(const float* __restrict__ Wq, const float* __restrict__ Wk,
            const float* __restrict__ Wv, const float* __restrict__ uw2,
            f16* __restrict__ pw) {
  const int m   = blockIdx.x * 256 + threadIdx.x;   // 0..8191
  const int mat = m >> 11;
  const int f   = (m >> 6) & 31;
  const int l   = m & 63;
  const int g = l >> 4, c = l & 15;
  const int k0i = f >> 3, n0i = f & 7;
  const float* W = (mat == 0) ? Wq : (mat == 1) ? Wk : (mat == 2) ? Wv : uw2;
  const float* p = W + (k0i * 32 + 8 * g) * D_N + n0i * 16 + c;
  f16x8 r;
  #pragma unroll
  for (int j = 0; j < 8; ++j) r[j] = (f16)p[j * D_N];
  *(f16x8*)(pw + (size_t)m * 8) = r;
}

// B-frag load from packed buffer: one 16B coalesced read (L2/L3-hot)
__device__ __forceinline__ f16x8 wfrag(const f16* __restrict__ pw, int mat,
                                       int k0i, int n0i, int lane) {
  return *(const f16x8*)(pw +
      (size_t)((((mat << 5) + (k0i << 3) + n0i) << 6) + lane) * 8);
}

// A-frag of X (gathered rows of re, f32): lane(g,c) holds X[t0+c][k0+8g+j]
__device__ __forceinline__ f16x8 ld_x_frag(const float* __restrict__ reb,
                                           const int* al, int t0, int k0,
                                           int g, int c) {
  const float* p = reb + (size_t)al[t0 + c] * D_N + k0 + 8 * g;
  float4 a = *(const float4*)p, b = *(const float4*)(p + 4);
  f16x8 r;
  r[0]=(f16)a.x; r[1]=(f16)a.y; r[2]=(f16)a.z; r[3]=(f16)a.w;
  r[4]=(f16)b.x; r[5]=(f16)b.y; r[6]=(f16)b.z; r[7]=(f16)b.w;
  return r;
}

// K,V projection for one 16-row tile -> Kh / VT (LDS, swizzled)
__device__ __forceinline__ void kvproj(char* smraw, const float* __restrict__ reb,
                                       const f16* __restrict__ pw,
                                       int t0, int g, int c, int lane) {
  const int* al = (const int*)(smraw + OFF_AL);
  char* smK = smraw + OFF_KH;
  char* smV = smraw + OFF_VT;
  f16x8 xf[4];
  #pragma unroll
  for (int k0i = 0; k0i < 4; ++k0i) xf[k0i] = ld_x_frag(reb, al, t0, k0i << 5, g, c);
  #pragma unroll 2
  for (int n0i = 0; n0i < 8; ++n0i) {
    const int n = (n0i << 4) + c;
    f32x4 aK = {0.f,0.f,0.f,0.f}, aV = {0.f,0.f,0.f,0.f};
    #pragma unroll
    for (int k0i = 0; k0i < 4; ++k0i) {
      aK = MFMA(xf[k0i], wfrag(pw, MAT_WK, k0i, n0i, lane), aK);
      aV = MFMA(xf[k0i], wfrag(pw, MAT_WV, k0i, n0i, lane), aV);
    }
    #pragma unroll
    for (int r = 0; r < 4; ++r) {            // Kh[t][n], t = t0+4g+r
      const int t = t0 + (g << 2) + r;
      *(f16*)(smK + t * 256 + ((2 * n) ^ ((t & 7) << 4))) = (f16)fmaxf(aK[r], 0.f);
    }
    f16x4 pv;                                 // VT[n][t0+4g .. +3] (8B store)
    #pragma unroll
    for (int r = 0; r < 4; ++r) pv[r] = (f16)fmaxf(aV[r], 0.f);
    *(f16x4*)(smV + n * 512 + ((2 * (t0 + (g << 2))) ^ ((n & 7) << 4))) = pv;
  }
}

// One q-tile: Q-proj + flash attention + (STAMP ? stamp-epilogue : declast)
template <bool STAMP>
__device__ __forceinline__ void attention_tile(
    char* smraw, const float* __restrict__ reb,
    const f16* __restrict__ pw,
    int t0, int len, int NS, int g, int c, int w, int lane,
    float (&out1p)[8], int tlast) {
  const int* al = (const int*)(smraw + OFF_AL);
  char* scr = smraw + OFF_SCR + (w << 12);
  char* smK = smraw + OFF_KH;
  char* smV = smraw + OFF_VT;

  // ---- Q projection -> A-frags (via per-wave scratch bounce) ----
  f16x8 qf[4];
  {
    f16x8 xf[4];
    #pragma unroll
    for (int k0i = 0; k0i < 4; ++k0i) xf[k0i] = ld_x_frag(reb, al, t0, k0i << 5, g, c);
    #pragma unroll 2
    for (int n0i = 0; n0i < 8; ++n0i) {
      f32x4 acc = {0.f,0.f,0.f,0.f};
      #pragma unroll
      for (int k0i = 0; k0i < 4; ++k0i)
        acc = MFMA(xf[k0i], wfrag(pw, MAT_WQ, k0i, n0i, lane), acc);
      #pragma unroll
      for (int r = 0; r < 4; ++r) {
        const int row = (g << 2) + r;
        *(f16*)(scr + row * 256 + ((2 * ((n0i << 4) + c)) ^ ((row & 7) << 4))) =
            (f16)fmaxf(acc[r], 0.f);
      }
    }
    #pragma unroll
    for (int k0i = 0; k0i < 4; ++k0i)
      qf[k0i] = *(const f16x8*)(scr + c * 256 +
                                ((2 * (k0i << 5) + 16 * g) ^ ((c & 7) << 4)));
  }

  // ---- flash attention over 32-col s-pairs ----
  f32x4 dacc[8];
  #pragma unroll
  for (int i = 0; i < 8; ++i) dacc[i] = f32x4{0.f,0.f,0.f,0.f};
  float m_run[4] = {FNEG, FNEG, FNEG, FNEG};
  float l_run[4] = {0.f, 0.f, 0.f, 0.f};
  const int npair = (NS + 1) >> 1;

  for (int p = 0; p < npair; ++p) {
    const int s0 = p << 5;
    const bool hasB = (2 * p + 1) < NS;
    f32x4 sA = {0.f,0.f,0.f,0.f}, sB = {0.f,0.f,0.f,0.f};
    {
      const int sa = s0 + c;
      const int swa = (sa & 7) << 4;
      #pragma unroll
      for (int k0i = 0; k0i < 4; ++k0i)
        sA = MFMA(qf[k0i],
                  *(const f16x8*)(smK + sa * 256 + ((2*(k0i<<5) + 16*g) ^ swa)), sA);
    }
    if (hasB) {
      const int sb = s0 + 16 + c;
      const int swb = (sb & 7) << 4;
      #pragma unroll
      for (int k0i = 0; k0i < 4; ++k0i)
        sB = MFMA(qf[k0i],
                  *(const f16x8*)(smK + sb * 256 + ((2*(k0i<<5) + 16*g) ^ swb)), sB);
    }
    float corr[4];
    #pragma unroll
    for (int r = 0; r < 4; ++r) {
      float a  = (s0 + c < len)                ? sA[r] * SCALE : FNEG;
      float bq = (hasB && (s0 + 16 + c < len)) ? sB[r] * SCALE : FNEG;
      float mx = fmaxf(a, bq);
      mx = fmaxf(mx, __shfl_xor(mx, 1, 64));
      mx = fmaxf(mx, __shfl_xor(mx, 2, 64));
      mx = fmaxf(mx, __shfl_xor(mx, 4, 64));
      mx = fmaxf(mx, __shfl_xor(mx, 8, 64));
      const float mnew = fmaxf(m_run[r], mx);
      const float cr = __expf(m_run[r] - mnew);
      const float pa = __expf(a - mnew);
      const float pb = __expf(bq - mnew);
      float rs = pa + pb;
      rs += __shfl_xor(rs, 1, 64); rs += __shfl_xor(rs, 2, 64);
      rs += __shfl_xor(rs, 4, 64); rs += __shfl_xor(rs, 8, 64);
      l_run[r] = l_run[r] * cr + rs;
      m_run[r] = mnew; corr[r] = cr;
      const int row = (g << 2) + r;              // P -> scratch (D->A bounce)
      char* rb = scr + row * 256;
      const int sw = (row & 7) << 4;
      *(f16*)(rb + ((2 * c) ^ sw))        = (f16)pa;
      *(f16*)(rb + ((2 * (16 + c)) ^ sw)) = (f16)pb;
    }
    #pragma unroll
    for (int i = 0; i < 8; ++i) {
      dacc[i][0] *= corr[0]; dacc[i][1] *= corr[1];
      dacc[i][2] *= corr[2]; dacc[i][3] *= corr[3];
    }
    f16x8 pf = *(const f16x8*)(scr + c * 256 + ((16 * g) ^ ((c & 7) << 4)));
    #pragma unroll
    for (int n0i = 0; n0i < 8; ++n0i) {
      const int n = (n0i << 4) + c;
      f16x8 vf = *(const f16x8*)(smV + n * 512 + ((2 * s0 + 16 * g) ^ ((n & 7) << 4)));
      dacc[n0i] = MFMA(pf, vf, dacc[n0i]);
    }
  }

  // ---- finalize: normalize + residual (f32 from global) ----
  float rl[4];
  #pragma unroll
  for (int r = 0; r < 4; ++r) rl[r] = 1.0f / l_run[r];
  #pragma unroll
  for (int n0i = 0; n0i < 8; ++n0i) {
    #pragma unroll
    for (int r = 0; r < 4; ++r) {
      const int t = t0 + (g << 2) + r;
      const float xv = reb[(size_t)al[t] * D_N + (n0i << 4) + c];
      dacc[n0i][r] = dacc[n0i][r] * rl[r] + xv;
    }
  }

  if (!STAMP) {                                // pass0: emit dec[len-1] row
    float* dl = (float*)(smraw + OFF_DL);
    const int rho = tlast & 15;
    if ((rho >> 2) == g) {
      const int r0 = rho & 3;
      #pragma unroll
      for (int n0i = 0; n0i < 8; ++n0i) {
        const float v = (r0 == 0) ? dacc[n0i][0] : (r0 == 1) ? dacc[n0i][1]
                      : (r0 == 2) ? dacc[n0i][2] : dacc[n0i][3];
        dl[(n0i << 4) + c] = v;
      }
    }
    return;
  }

  // ---- STAMP: seq_p = dec @ u_w2 (MFMA via bounce), sigmoid, coef, out1 ----
  #pragma unroll
  for (int n0i = 0; n0i < 8; ++n0i) {
    #pragma unroll
    for (int r = 0; r < 4; ++r) {
      const int row = (g << 2) + r;
      *(f16*)(scr + row * 256 + ((2 * ((n0i << 4) + c)) ^ ((row & 7) << 4))) =
          (f16)dacc[n0i][r];
    }
  }
  f16x8 da[4];
  #pragma unroll
  for (int k0i = 0; k0i < 4; ++k0i)
    da[k0i] = *(const f16x8*)(scr + c * 256 +
                              ((2 * (k0i << 5) + 16 * g) ^ ((c & 7) << 4)));
  const float* lp  = (const float*)(smraw + OFF_LP);
  const float* ubp = (const float*)(smraw + OFF_UB);
  const float* uvp = (const float*)(smraw + OFF_UV);
  float cs[4] = {0.f, 0.f, 0.f, 0.f};
  #pragma unroll 2
  for (int n0i = 0; n0i < 8; ++n0i) {
    f32x4 sp = {0.f,0.f,0.f,0.f};
    #pragma unroll
    for (int k0i = 0; k0i < 4; ++k0i)
      sp = MFMA(da[k0i], wfrag(pw, MAT_W2, k0i, n0i, lane), sp);
    const int n = (n0i << 4) + c;
    const float add = lp[n] + ubp[n];
    const float uvn = uvp[n];
    #pragma unroll
    for (int r = 0; r < 4; ++r) {
      const float sig = 1.0f / (1.0f + __expf(-(sp[r] + add)));
      cs[r] += sig * uvn;
    }
  }
  #pragma unroll
  for (int r = 0; r < 4; ++r) {
    float cf = cs[r];
    cf += __shfl_xor(cf, 1, 64); cf += __shfl_xor(cf, 2, 64);
    cf += __shfl_xor(cf, 4, 64); cf += __shfl_xor(cf, 8, 64);
    const int t = t0 + (g << 2) + r;
    cf = (t < len) ? cf : 0.f;
    #pragma unroll
    for (int n0i = 0; n0i < 8; ++n0i) out1p[n0i] += cf * dacc[n0i][r];
  }
}

__global__ __launch_bounds__(512)
__attribute__((amdgpu_waves_per_eu(2, 2)))   // VGPR budget 256; LDS caps at 2 waves/SIMD anyway
void stamp_mfma(const float* __restrict__ re, const int* __restrict__ aliasg,
                const int* __restrict__ slen,
                const float* __restrict__ uw1, const float* __restrict__ ub,
                const float* __restrict__ uv, const f16* __restrict__ pw,
                float* __restrict__ out) {
  extern __shared__ char smraw[];
  const int tid  = threadIdx.x;
  const int lane = tid & 63;
  const int w    = tid >> 6;
  const int g    = lane >> 4;
  const int c    = lane & 15;
  const int b    = blockIdx.x;
  const int len  = slen[b];
  const int NS    = (len + 15) >> 4;            // 16-tiles covering [0,len)
  const int NPROJ = (NS + (NS & 1) < 13) ? NS + (NS & 1) : 13;
  const int tlast = len - 1;
  const float* __restrict__ reb = re + (size_t)b * (T_N * D_N);

  // ---- init LDS ----
  if (tid < 208) ((int*)(smraw + OFF_AL))[tid] = (tid < T_N) ? aliasg[b * T_N + tid] : 0;
  if (tid < 128) {
    ((float*)(smraw + OFF_UB))[tid] = ub[tid];
    ((float*)(smraw + OFF_UV))[tid] = uv[tid];
    // zero VT cols [208,224) (tail PV B-frags may touch them)
    f16x8 z = {};
    char* vrow = smraw + OFF_VT + tid * 512;
    const int sw = (tid & 7) << 4;
    *(f16x8*)(vrow + (416 ^ sw)) = z;
    *(f16x8*)(vrow + (432 ^ sw)) = z;
  }
  __syncthreads();

  // ---- K,V projections (tiles split across waves) ----
  for (int mt = w; mt < NPROJ; mt += 8)
    kvproj(smraw, reb, pw, mt << 4, g, c, lane);
  __syncthreads();                              // Kh, VT complete

  // ---- pass0: dec[len-1] -> declast ----
  float dummy[8] = {0,0,0,0,0,0,0,0};
  const int TL = tlast >> 4;
  if (w == (TL & 7))
    attention_tile<false>(smraw, reb, pw, TL << 4, len, NS, g, c, w, lane,
                          dummy, tlast);
  __syncthreads();

  // ---- lastp = declast @ u_w1 (cooperative), emit out[:,128:256] ----
  {
    const int j = tid & 127, seg = tid >> 7;
    const float* dl = (const float*)(smraw + OFF_DL);
    float acc = 0.f;
    for (int i = 0; i < 32; ++i) {
      const int d = (seg << 5) + i;
      acc += dl[d] * uw1[d * D_N + j];
    }
    ((float*)(smraw + OFF_LR))[(seg << 7) + j] = acc;
  }
  __syncthreads();
  if (tid < 128) {
    const float* lr = (const float*)(smraw + OFF_LR);
    const float v = lr[tid] + lr[128 + tid] + lr[256 + tid] + lr[384 + tid];
    ((float*)(smraw + OFF_LP))[tid] = v;
    out[(size_t)b * 256 + 128 + tid] = v;
  }
  __syncthreads();                              // lastp visible

  // ---- pass1: all q-tiles, wave-independent ----
  float out1p[8] = {0.f,0.f,0.f,0.f,0.f,0.f,0.f,0.f};
  for (int qt = w; qt < NS; qt += 8)
    attention_tile<true>(smraw, reb, pw, qt << 4, len, NS, g, c, w, lane,
                         out1p, tlast);

  // ---- out1 reduction ----
  #pragma unroll
  for (int i = 0; i < 8; ++i) {
    out1p[i] += __shfl_xor(out1p[i], 16, 64);
    out1p[i] += __shfl_xor(out1p[i], 32, 64);
  }
  float* wr = (float*)(smraw + OFF_WR) + (w << 7);
  if (g == 0) {
    #pragma unroll
    for (int i = 0; i < 8; ++i) wr[(i << 4) + c] = out1p[i];
  }
  __syncthreads();
  if (tid < 128) {
    const float* wrb = (const float*)(smraw + OFF_WR);
    float s = 0.f;
    #pragma unroll
    for (int ww = 0; ww < 8; ++ww) s += wrb[(ww << 7) + tid];
    out[(size_t)b * 256 + tid] = s;
  }
}

extern "C" void kernel_launch(void* const* d_in, const int* in_sizes, int n_in,
                              void* d_out, int out_size, void* d_ws, size_t ws_size,
                              hipStream_t stream) {
  (void)n_in; (void)out_size; (void)ws_size;
  const float* re    = (const float*)d_in[0];
  const int*   alias = (const int*)  d_in[1];
  const int*   slen  = (const int*)  d_in[2];
  const float* Wq    = (const float*)d_in[3];
  const float* Wk    = (const float*)d_in[4];
  const float* Wv    = (const float*)d_in[5];
  const float* uw1   = (const float*)d_in[6];
  const float* uw2   = (const float*)d_in[7];
  const float* ub    = (const float*)d_in[8];
  const float* uv    = (const float*)d_in[9];
  float* out = (float*)d_out;
  const int B = in_sizes[2];

  f16* pw = (f16*)d_ws;                 // 128 KB packed weights (ws verified >=)
  pack_w<<<32, 256, 0, stream>>>(Wq, Wk, Wv, uw2, pw);
  hipFuncSetAttribute(reinterpret_cast<const void*>(&stamp_mfma),
                      hipFuncAttributeMaxDynamicSharedMemorySize, LDS_TOTAL);
  stamp_mfma<<<B, 512, LDS_TOTAL, stream>>>(re, alias, slen, uw1, ub, uv, pw, out);
}